// Round 12
// baseline (383.266 us; speedup 1.0000x reference)
//
#include <hip/hip_runtime.h>
#include <hip/hip_bf16.h>
#include <math.h>

typedef __bf16 bf16;
typedef __attribute__((ext_vector_type(8))) __bf16 bf16x8;
typedef __attribute__((ext_vector_type(4))) __bf16 bf16x4;
typedef __attribute__((ext_vector_type(4))) float f32x4;
typedef __attribute__((ext_vector_type(4))) short short4v;

#define HDIM 1024
#define NHEAD 16
#define HD 64
#define FFDIM 4096
#define BATCH 2
#define SEQ 2048
#define M_TOK 4096  // BATCH*SEQ
#define NSPLIT 4
#define PSTRIDE ((size_t)M_TOK * HDIM)  // elements between split-K partials

static __device__ __forceinline__ void async_load16(const bf16* g, bf16* l) {
  __builtin_amdgcn_global_load_lds(
      (const __attribute__((address_space(1))) void*)g,
      (__attribute__((address_space(3))) void*)l, 16, 0, 0);
}

// 16x16x16 bf16 MFMA wrapper. Host pass has no amdgcn builtins -> gate on
// __HIP_DEVICE_COMPILE__ (R5 lesson).
static __device__ __forceinline__ f32x4 mfma16_bf16(bf16x4 a, bf16x4 b, f32x4 c) {
#if defined(__HIP_DEVICE_COMPILE__)
#if __has_builtin(__builtin_amdgcn_mfma_f32_16x16x16bf16_1k)
  return __builtin_amdgcn_mfma_f32_16x16x16bf16_1k(
      __builtin_bit_cast(short4v, a), __builtin_bit_cast(short4v, b), c, 0, 0, 0);
#else
  return __builtin_amdgcn_mfma_f32_16x16x16_bf16(a, b, c, 0, 0, 0);
#endif
#else
  return c;  // host pass: never executed
#endif
}

// ---------------------------------------------------------------- prep: QKVO transposes + x cast
// z 0..3: Wq/Wk/Wv/Wo 1024x1024 -> QKVT + z*1M; z 4: cast x -> Xb
__global__ __launch_bounds__(256)
void prep_kernel(const float* __restrict__ x,
                 const float* __restrict__ Wq, const float* __restrict__ Wk,
                 const float* __restrict__ Wv, const float* __restrict__ Wo,
                 bf16* __restrict__ Xb, bf16* __restrict__ QKVT)
{
  const int z = blockIdx.z;
  const int t = threadIdx.x;
  if (z == 4) {
    const size_t base = ((size_t)(blockIdx.y * 32 + blockIdx.x)) * 4096;
#pragma unroll
    for (int j = 0; j < 4; ++j) {
      const size_t i = base + j * 1024 + t * 4;
      f32x4 v = *(const f32x4*)(x + i);
      bf16x4 o;
#pragma unroll
      for (int k = 0; k < 4; ++k) o[k] = (bf16)v[k];
      *(bf16x4*)(Xb + i) = o;
    }
    return;
  }
  const float* ps = (z == 0) ? Wq : (z == 1) ? Wk : (z == 2) ? Wv : Wo;
  bf16* pd = QKVT + (size_t)z * HDIM * HDIM;
  __shared__ float tile[32][33];
  const int tx = t & 31, ty = t >> 5;
  const int c0 = blockIdx.x * 32, r0 = blockIdx.y * 32;
#pragma unroll
  for (int i = 0; i < 32; i += 8)
    tile[ty + i][tx] = ps[(size_t)(r0 + ty + i) * HDIM + c0 + tx];
  __syncthreads();
#pragma unroll
  for (int i = 0; i < 32; i += 8)
    pd[(size_t)(c0 + ty + i) * HDIM + r0 + tx] = (bf16)tile[tx][ty + i];
}

// ---------------------------------------------------------------- GEMM  C = A @ Bt^T (+ bias)
// Operand-swapped MFMA: lane holds 4 consecutive output columns -> vector stores.
// EPI: 1 = bf16 partial (no bias, out + z*M*N), 2 = bias+gelu(A&S erf)->bf16
template<int EPI>
__global__ __launch_bounds__(256)
void gemm_bt(const bf16* __restrict__ A, const bf16* __restrict__ Bt,
             const float* __restrict__ b0, void* __restrict__ Cout,
             int M, int N, int ldk, int kchunk)
{
  __shared__ __align__(16) bf16 As[128 * 64];
  __shared__ __align__(16) bf16 Bs[128 * 64];
  const int t = threadIdx.x;
  const int wave = t >> 6, lane = t & 63;
  const int lm = lane & 15, qd = lane >> 4;
  const int wm = (wave >> 1) * 64, wn = (wave & 1) * 64;
  const int bm = blockIdx.y * 128, bn = blockIdx.x * 128;
  const int kbeg = blockIdx.z * kchunk;

  f32x4 acc[4][4] = {};
  const int srow = t >> 3;
  const int schk = t & 7;

  for (int k0 = kbeg; k0 < kbeg + kchunk; k0 += 64) {
#pragma unroll
    for (int r = 0; r < 4; ++r) {
      const int row = r * 32 + srow;
      const int chunk = schk ^ (row & 7);
      async_load16(A + (size_t)(bm + row) * ldk + (k0 + chunk * 8),
                   (bf16*)((char*)As + r * 4096 + t * 16));
    }
#pragma unroll
    for (int r = 0; r < 4; ++r) {
      const int row = r * 32 + srow;
      const int chunk = schk ^ (row & 7);
      async_load16(Bt + (size_t)(bn + row) * ldk + (k0 + chunk * 8),
                   (bf16*)((char*)Bs + r * 4096 + t * 16));
    }
    __syncthreads();
#pragma unroll
    for (int ks = 0; ks < 2; ++ks) {
      bf16x8 av[4], bv[4];
#pragma unroll
      for (int mt = 0; mt < 4; ++mt) {
        const int row = wm + mt * 16 + lm;
        const int chunk = (ks * 4 + qd) ^ (row & 7);
        av[mt] = *(const bf16x8*)(As + row * 64 + chunk * 8);
      }
#pragma unroll
      for (int nt = 0; nt < 4; ++nt) {
        const int row = wn + nt * 16 + lm;
        const int chunk = (ks * 4 + qd) ^ (row & 7);
        bv[nt] = *(const bf16x8*)(Bs + row * 64 + chunk * 8);
      }
#pragma unroll
      for (int mt = 0; mt < 4; ++mt)
#pragma unroll
        for (int nt = 0; nt < 4; ++nt)
          acc[mt][nt] = __builtin_amdgcn_mfma_f32_16x16x32_bf16(bv[nt], av[mt], acc[mt][nt], 0, 0, 0);
    }
    __syncthreads();
  }

#pragma unroll
  for (int nt = 0; nt < 4; ++nt) {
    const int n0 = bn + wn + nt * 16 + qd * 4;
    f32x4 bsv = {0.f, 0.f, 0.f, 0.f};
    if (EPI == 2) bsv = *(const f32x4*)(b0 + n0);
#pragma unroll
    for (int mt = 0; mt < 4; ++mt) {
      const int m = bm + wm + mt * 16 + lm;
      f32x4 v;
#pragma unroll
      for (int r = 0; r < 4; ++r) v[r] = acc[mt][nt][r] + bsv[r];
      if (EPI == 1) {
        bf16x4 o;
#pragma unroll
        for (int r = 0; r < 4; ++r) o[r] = (bf16)v[r];
        *(bf16x4*)((bf16*)Cout + (size_t)blockIdx.z * M * N + (size_t)m * N + n0) = o;
      } else {
        bf16x4 o;
#pragma unroll
        for (int r = 0; r < 4; ++r) {
          const float z = v[r] * 0.70710678118f;
          const float az = fabsf(z);
          const float tt = __builtin_amdgcn_rcpf(fmaf(az, 0.3275911f, 1.0f));
          const float poly = tt * fmaf(tt, fmaf(tt, fmaf(tt, fmaf(tt, 1.061405429f,
                             -1.453152027f), 1.421413741f), -0.284496736f), 0.254829592f);
          const float e = __builtin_amdgcn_exp2f(az * az * -1.4426950408889634f);
          float erfv = 1.0f - poly * e;
          erfv = (z < 0.f) ? -erfv : erfv;
          o[r] = (bf16)(0.5f * v[r] * (1.0f + erfv));
        }
        *(bf16x4*)((bf16*)Cout + (size_t)m * N + n0) = o;
      }
    }
  }
}

// ----------------------------------------- QKV GEMM (fused epilogue) + W1/W2 transposes
// x < 24: 128x128 GEMM tile of X @ QKVT^T (Q/K std layout, V -> Vt[d][s]).
// x >= 24: transpose blocks (id = (x-24)+32*y, 8 tiles each) for W1T/W2T,
// float tile aliased into As (GEMM path LDS/VGPR footprint unchanged — R11 lesson).
__global__ __launch_bounds__(256)
void gemm_qkv_tr(const bf16* __restrict__ A, const bf16* __restrict__ Bt,
                 const float* __restrict__ b0, const float* __restrict__ b1p,
                 const float* __restrict__ b2p, bf16* __restrict__ Cout,
                 const float* __restrict__ W1, const float* __restrict__ W2,
                 bf16* __restrict__ W1T, bf16* __restrict__ W2T)
{
  __shared__ __align__(16) bf16 As[128 * 64];
  __shared__ __align__(16) bf16 Bs[128 * 64];
  const int t = threadIdx.x;

  if (blockIdx.x >= 24) {
    // transpose path: 1024 blocks x 8 tiles = 8192 32x32 tiles (W1 then W2)
    float (*tile)[33] = (float(*)[33])As;
    const int id = (blockIdx.x - 24) + 32 * blockIdx.y;
    const int tx = t & 31, ty = t >> 5;
#pragma unroll
    for (int r = 0; r < 8; ++r) {
      const int g = id * 8 + r;
      const float* ps; bf16* pd; int sld, dld;
      if (g < 4096) {
        const int c = g >> 10;
        ps = W1 + c * 1024; sld = 4096;
        pd = W1T + ((size_t)c << 20); dld = 1024;
      } else {
        const int c = (g - 4096) >> 10;
        ps = W2 + ((size_t)c << 20); sld = 1024;
        pd = W2T + c * 1024; dld = 4096;
      }
      const int rr = g & 1023;
      const int c0 = (rr & 31) * 32, r0 = (rr >> 5) * 32;
      if (r) __syncthreads();
#pragma unroll
      for (int i = 0; i < 32; i += 8)
        tile[ty + i][tx] = ps[(size_t)(r0 + ty + i) * sld + c0 + tx];
      __syncthreads();
#pragma unroll
      for (int i = 0; i < 32; i += 8)
        pd[(size_t)(c0 + ty + i) * dld + r0 + tx] = (bf16)tile[tx][ty + i];
    }
    return;
  }

  const int wave = t >> 6, lane = t & 63;
  const int lm = lane & 15, qd = lane >> 4;
  const int wm = (wave >> 1) * 64, wn = (wave & 1) * 64;
  const int bm = blockIdx.y * 128, bn = blockIdx.x * 128;

  f32x4 acc[4][4] = {};
  const int srow = t >> 3;
  const int schk = t & 7;

  for (int k0 = 0; k0 < HDIM; k0 += 64) {
#pragma unroll
    for (int r = 0; r < 4; ++r) {
      const int row = r * 32 + srow;
      const int chunk = schk ^ (row & 7);
      async_load16(A + (size_t)(bm + row) * HDIM + (k0 + chunk * 8),
                   (bf16*)((char*)As + r * 4096 + t * 16));
    }
#pragma unroll
    for (int r = 0; r < 4; ++r) {
      const int row = r * 32 + srow;
      const int chunk = schk ^ (row & 7);
      async_load16(Bt + (size_t)(bn + row) * HDIM + (k0 + chunk * 8),
                   (bf16*)((char*)Bs + r * 4096 + t * 16));
    }
    __syncthreads();
#pragma unroll
    for (int ks = 0; ks < 2; ++ks) {
      bf16x8 av[4], bv[4];
#pragma unroll
      for (int mt = 0; mt < 4; ++mt) {
        const int row = wm + mt * 16 + lm;
        const int chunk = (ks * 4 + qd) ^ (row & 7);
        av[mt] = *(const bf16x8*)(As + row * 64 + chunk * 8);
      }
#pragma unroll
      for (int nt = 0; nt < 4; ++nt) {
        const int row = wn + nt * 16 + lm;
        const int chunk = (ks * 4 + qd) ^ (row & 7);
        bv[nt] = *(const bf16x8*)(Bs + row * 64 + chunk * 8);
      }
#pragma unroll
      for (int mt = 0; mt < 4; ++mt)
#pragma unroll
        for (int nt = 0; nt < 4; ++nt)
          acc[mt][nt] = __builtin_amdgcn_mfma_f32_16x16x32_bf16(bv[nt], av[mt], acc[mt][nt], 0, 0, 0);
    }
    __syncthreads();
  }

#pragma unroll
  for (int nt = 0; nt < 4; ++nt) {
    const int n0 = bn + wn + nt * 16 + qd * 4;
    const int sect = n0 >> 10, c = n0 & 1023;
    const float* bp = (sect == 0) ? b0 : (sect == 1) ? b1p : b2p;
    f32x4 bsv = *(const f32x4*)(bp + c);
#pragma unroll
    for (int mt = 0; mt < 4; ++mt) {
      const int m = bm + wm + mt * 16 + lm;
      f32x4 v;
#pragma unroll
      for (int r = 0; r < 4; ++r) v[r] = acc[mt][nt][r] + bsv[r];
      if (sect < 2) {
        bf16x4 o;
#pragma unroll
        for (int r = 0; r < 4; ++r) o[r] = (bf16)v[r];
        *(bf16x4*)(Cout + (size_t)sect * M_TOK * HDIM + (size_t)m * HDIM + c) = o;
      } else {
        const int hh = c >> 6, dd = c & 63;
        const int bb = m >> 11, ss = m & 2047;
#pragma unroll
        for (int r = 0; r < 4; ++r)
          Cout[(size_t)2 * M_TOK * HDIM +
               (size_t)((bb * NHEAD + hh) * HD + dd + r) * SEQ + ss] = (bf16)v[r];
      }
    }
  }
}

// ---------------------------------------------------------------- flash attention (R10)
// LDS-staged K/V (64-key tiles), register-P, 32 q/wave, NSPLIT=4, bf16 partials.
// grid (SEQ/128, 32 bh, NSPLIT), 256 thr.
__global__ __launch_bounds__(256)
void attn_kernel(const bf16* __restrict__ Q, const bf16* __restrict__ Kg,
                 const bf16* __restrict__ Vt, const int* __restrict__ mask,
                 bf16* __restrict__ Po, float* __restrict__ Lp)
{
  __shared__ __align__(16) bf16 Ks[64 * 64];   // [key][d], chunk-swizzled
  __shared__ __align__(16) bf16 Vs[64 * 64];   // [d][key], chunk-swizzled
  __shared__ float madd[64];

  const int t = threadIdx.x;
  const int wave = t >> 6, lane = t & 63;
  const int lm = lane & 15, qd = lane >> 4;
  const int bh = blockIdx.y;
  const int b = bh >> 4, h = bh & 15;
  const int q0 = blockIdx.x * 128 + wave * 32;
  const int split = blockIdx.z;
  const int kv_beg = split * (SEQ / NSPLIT);

  bf16x8 qf[2][2];
#pragma unroll
  for (int qt = 0; qt < 2; ++qt)
#pragma unroll
    for (int ks = 0; ks < 2; ++ks)
      qf[qt][ks] = *(const bf16x8*)(Q + (size_t)(b * SEQ + q0 + qt * 16 + lm) * HDIM +
                                    h * HD + ks * 32 + qd * 8);

  float l_lane[2] = {0.f, 0.f};
  f32x4 oacc[2][4] = {};   // [qt][nt2] O^T: d = nt2*16+qd*4+r, q = lm

  const int srow = t >> 3, schk = t & 7;
  const float C = 0.1803368801f;  // log2(e)/8

  for (int kv0 = kv_beg; kv0 < kv_beg + SEQ / NSPLIT; kv0 += 64) {
#pragma unroll
    for (int r = 0; r < 2; ++r) {
      const int row = r * 32 + srow;
      const int g = schk ^ (row & 7);
      async_load16(Kg + (size_t)(b * SEQ + kv0 + row) * HDIM + h * HD + g * 8,
                   (bf16*)((char*)Ks + r * 4096 + t * 16));
      async_load16(Vt + (size_t)(bh * HD + row) * SEQ + kv0 + g * 8,
                   (bf16*)((char*)Vs + r * 4096 + t * 16));
    }
    if (t < 64) madd[t] = (mask[b * SEQ + kv0 + t] == 1) ? 0.f : -1.0e30f;
    __syncthreads();

    bf16x8 kf[2][4];
#pragma unroll
    for (int ks = 0; ks < 2; ++ks)
#pragma unroll
      for (int nt = 0; nt < 4; ++nt) {
        const int row = nt * 16 + lm;
        const int c = (ks * 4 + qd) ^ (row & 7);
        kf[ks][nt] = *(const bf16x8*)(Ks + row * 64 + c * 8);
      }

    bf16x4 pf[2][4];
#pragma unroll
    for (int qt = 0; qt < 2; ++qt) {
      f32x4 sacc[4] = {};
#pragma unroll
      for (int ks = 0; ks < 2; ++ks)
#pragma unroll
        for (int nt = 0; nt < 4; ++nt)
          sacc[nt] = __builtin_amdgcn_mfma_f32_16x16x32_bf16(kf[ks][nt], qf[qt][ks], sacc[nt], 0, 0, 0);
#pragma unroll
      for (int nt = 0; nt < 4; ++nt) {
        f32x4 ma = *(const f32x4*)(madd + nt * 16 + qd * 4);
#pragma unroll
        for (int r = 0; r < 4; ++r) {
          const float pv = __builtin_amdgcn_exp2f(fmaf(sacc[nt][r], C, ma[r]));
          l_lane[qt] += pv;
          pf[qt][nt][r] = (bf16)pv;
        }
      }
    }

#pragma unroll
    for (int nt2 = 0; nt2 < 4; ++nt2) {
      const int row = nt2 * 16 + lm;
#pragma unroll
      for (int nt = 0; nt < 4; ++nt) {
        bf16x4 vf = *(const bf16x4*)(Vs + row * 64 +
                     (((nt * 2 + (qd >> 1)) ^ (row & 7)) * 8) + (qd & 1) * 4);
        oacc[0][nt2] = mfma16_bf16(vf, pf[0][nt], oacc[0][nt2]);
        oacc[1][nt2] = mfma16_bf16(vf, pf[1][nt], oacc[1][nt2]);
      }
    }
    __syncthreads();
  }

  bf16* po = Po + (size_t)(split * 32 + bh) * 64 * SEQ;
#pragma unroll
  for (int qt = 0; qt < 2; ++qt) {
    float l = l_lane[qt];
    l += __shfl_xor(l, 16, 64);
    l += __shfl_xor(l, 32, 64);
#pragma unroll
    for (int nt2 = 0; nt2 < 4; ++nt2)
#pragma unroll
      for (int r = 0; r < 4; ++r)
        po[(size_t)(nt2 * 16 + qd * 4 + r) * SEQ + q0 + qt * 16 + lm] =
            (bf16)oacc[qt][nt2][r];
    if (qd == 0)
      Lp[(size_t)(split * 32 + bh) * SEQ + q0 + qt * 16 + lm] = l;
  }
}

// ---------------------------------------------------------------- attn merge: O = (sum Po_s)/(sum l_s)
__global__ __launch_bounds__(256)
void attn_merge(const bf16* __restrict__ Po, const float* __restrict__ Lp,
                bf16* __restrict__ Aout)
{
  const int t = threadIdx.x;
  const int bh = blockIdx.y;
  const int b = bh >> 4, h = bh & 15;
  const int s0 = blockIdx.x * 64;
  const int tok = t >> 2;
  const int dc = (t & 3) * 16;

  float l = 0.f;
#pragma unroll
  for (int s = 0; s < NSPLIT; ++s)
    l += Lp[(size_t)(s * 32 + bh) * SEQ + s0 + tok];
  const float inv = 1.0f / l;

  const bf16* ps[NSPLIT];
#pragma unroll
  for (int s = 0; s < NSPLIT; ++s)
    ps[s] = Po + (size_t)(s * 32 + bh) * 64 * SEQ + s0 + tok;

  bf16x8 o0, o1;
#pragma unroll
  for (int j = 0; j < 16; ++j) {
    float acc = 0.f;
#pragma unroll
    for (int s = 0; s < NSPLIT; ++s)
      acc += (float)ps[s][(size_t)(dc + j) * SEQ];
    const bf16 ov = (bf16)(acc * inv);
    if (j < 8) o0[j] = ov; else o1[j - 8] = ov;
  }

  bf16* dst = Aout + (size_t)(b * SEQ + s0 + tok) * HDIM + h * HD + dc;
  *(bf16x8*)dst = o0;
  *(bf16x8*)(dst + 8) = o1;
}

// ------------------------------- layernorm over H=1024, summing NP bf16 partials + bias
template<int NP, int OUT_BF16>
__global__ __launch_bounds__(256)
void ln_sum(const bf16* __restrict__ p, const float* __restrict__ bias,
            const float* __restrict__ gamma, const float* __restrict__ beta,
            void* __restrict__ out)
{
  const int row = blockIdx.x;
  const int t = threadIdx.x;
  f32x4 v = {0.f, 0.f, 0.f, 0.f};
#pragma unroll
  for (int np = 0; np < NP; ++np) {
    bf16x4 u = *(const bf16x4*)(p + np * PSTRIDE + (size_t)row * HDIM + t * 4);
#pragma unroll
    for (int j = 0; j < 4; ++j) v[j] += (float)u[j];
  }
  f32x4 bv0 = *(const f32x4*)(bias + t * 4);
#pragma unroll
  for (int j = 0; j < 4; ++j) v[j] += bv0[j];

  float s = v[0] + v[1] + v[2] + v[3];
  float s2 = v[0] * v[0] + v[1] * v[1] + v[2] * v[2] + v[3] * v[3];
#pragma unroll
  for (int d = 1; d < 64; d <<= 1) { s += __shfl_xor(s, d, 64); s2 += __shfl_xor(s2, d, 64); }
  __shared__ float ss[4], ss2[4];
  const int wave = t >> 6, lane = t & 63;
  if (lane == 0) { ss[wave] = s; ss2[wave] = s2; }
  __syncthreads();
  s = ss[0] + ss[1] + ss[2] + ss[3];
  s2 = ss2[0] + ss2[1] + ss2[2] + ss2[3];
  const float mean = s * (1.0f / HDIM);
  const float var = s2 * (1.0f / HDIM) - mean * mean;
  const float rstd = rsqrtf(var + 1e-12f);
  f32x4 gv = *(const f32x4*)(gamma + t * 4);
  f32x4 bv = *(const f32x4*)(beta + t * 4);
  f32x4 y;
#pragma unroll
  for (int j = 0; j < 4; ++j) y[j] = gv[j] * (v[j] - mean) * rstd + bv[j];
  if (OUT_BF16) {
    bf16x4 o;
#pragma unroll
    for (int j = 0; j < 4; ++j) o[j] = (bf16)y[j];
    *(bf16x4*)((bf16*)out + (size_t)row * HDIM + t * 4) = o;
  } else {
    *(f32x4*)((float*)out + (size_t)row * HDIM + t * 4) = y;
  }
}

// ---------------------------------------------------------------- launch
extern "C" void kernel_launch(void* const* d_in, const int* in_sizes, int n_in,
                              void* d_out, int out_size, void* d_ws, size_t ws_size,
                              hipStream_t stream)
{
  const float* x    = (const float*)d_in[0];
  const int*   am   = (const int*)d_in[1];
  const float* Wq   = (const float*)d_in[2];
  const float* bq   = (const float*)d_in[3];
  const float* Wk   = (const float*)d_in[4];
  const float* bk   = (const float*)d_in[5];
  const float* Wv   = (const float*)d_in[6];
  const float* bv   = (const float*)d_in[7];
  const float* Wo   = (const float*)d_in[8];
  const float* bo   = (const float*)d_in[9];
  const float* ln1g = (const float*)d_in[10];
  const float* ln1b = (const float*)d_in[11];
  const float* W1   = (const float*)d_in[12];
  const float* b1   = (const float*)d_in[13];
  const float* W2   = (const float*)d_in[14];
  const float* b2   = (const float*)d_in[15];
  const float* ln2g = (const float*)d_in[16];
  const float* ln2b = (const float*)d_in[17];

  char* ws = (char*)d_ws;
  const size_t MB = 1ull << 20;
  bf16*  W1T  = (bf16*)(ws + 0 * MB);    // 8 MiB (written during QKV)
  bf16*  W2T  = (bf16*)(ws + 8 * MB);    // 8 MiB (written during QKV)
  bf16*  Xb   = (bf16*)(ws + 16 * MB);   // 8 MiB (dead after QKV)
  bf16*  QKVT = (bf16*)(ws + 24 * MB);   // 8 MiB (WoT = last quarter)
  bf16*  WoT  = QKVT + (size_t)3 * HDIM * HDIM;
  bf16*  Qb   = (bf16*)(ws + 33 * MB);   // Q(33-41), K(41-49), Vt(49-57)
  bf16*  Kb   = (bf16*)(ws + 41 * MB);
  bf16*  Vtb  = (bf16*)(ws + 49 * MB);
  bf16*  Po   = (bf16*)(ws + 57 * MB);   // 32 MiB attn O^T bf16 partials (57-89)
  float* Lp   = (float*)(ws + 89 * MB);  // 1 MiB l partials (4 splits)
  bf16*  Ab   = (bf16*)(ws + 16 * MB);   // merge out, reuse Xb
  bf16*  Pw   = (bf16*)(ws + 33 * MB);   // Wo bf16 partials 33-49 (Q/K dead)
  bf16*  L1   = (bf16*)(ws + 65 * MB);   // 8 MiB
  bf16*  F1   = (bf16*)(ws + 16 * MB);   // 32 MiB (16-48)
  bf16*  Pf   = (bf16*)(ws + 48 * MB);   // FFN2 bf16 partials 48-80

  prep_kernel<<<dim3(32, 32, 5), 256, 0, stream>>>(x, Wq, Wk, Wv, Wo, Xb, QKVT);

  // QKV GEMM (x<24) + W1/W2 transposes (x>=24) in one launch
  gemm_qkv_tr<<<dim3(24 + 32, 32, 1), 256, 0, stream>>>(
      Xb, QKVT, bq, bk, bv, Qb, W1, W2, W1T, W2T);

  attn_kernel<<<dim3(SEQ / 128, BATCH * NHEAD, NSPLIT), 256, 0, stream>>>(
      Qb, Kb, Vtb, am, Po, Lp);
  attn_merge<<<dim3(SEQ / 64, BATCH * NHEAD), 256, 0, stream>>>(Po, Lp, Ab);

  gemm_bt<1><<<dim3(HDIM / 128, M_TOK / 128, 2), 256, 0, stream>>>(
      Ab, WoT, nullptr, Pw, M_TOK, HDIM, HDIM, 512);
  ln_sum<2, 1><<<M_TOK, 256, 0, stream>>>(Pw, bo, ln1g, ln1b, L1);

  gemm_bt<2><<<dim3(FFDIM / 128, M_TOK / 128, 1), 256, 0, stream>>>(
      L1, W1T, b1, F1, M_TOK, FFDIM, HDIM, HDIM);

  gemm_bt<1><<<dim3(HDIM / 128, M_TOK / 128, 4), 256, 0, stream>>>(
      F1, W2T, nullptr, Pf, M_TOK, HDIM, FFDIM, 1024);
  ln_sum<4, 0><<<M_TOK, 256, 0, stream>>>(Pf, b2, ln2g, ln2b, (float*)d_out);
}

// Round 13
// 373.081 us; speedup vs baseline: 1.0273x; 1.0273x over previous
//
#include <hip/hip_runtime.h>
#include <hip/hip_bf16.h>
#include <math.h>

typedef __bf16 bf16;
typedef __attribute__((ext_vector_type(8))) __bf16 bf16x8;
typedef __attribute__((ext_vector_type(4))) __bf16 bf16x4;
typedef __attribute__((ext_vector_type(4))) float f32x4;
typedef __attribute__((ext_vector_type(4))) short short4v;

#define HDIM 1024
#define NHEAD 16
#define HD 64
#define FFDIM 4096
#define BATCH 2
#define SEQ 2048
#define M_TOK 4096  // BATCH*SEQ
#define NSPLIT 4
#define PSTRIDE ((size_t)M_TOK * HDIM)  // elements between split-K partials

static __device__ __forceinline__ void async_load16(const bf16* g, bf16* l) {
  __builtin_amdgcn_global_load_lds(
      (const __attribute__((address_space(1))) void*)g,
      (__attribute__((address_space(3))) void*)l, 16, 0, 0);
}

// 16x16x16 bf16 MFMA wrapper. Host pass has no amdgcn builtins -> gate on
// __HIP_DEVICE_COMPILE__ (R5 lesson).
static __device__ __forceinline__ f32x4 mfma16_bf16(bf16x4 a, bf16x4 b, f32x4 c) {
#if defined(__HIP_DEVICE_COMPILE__)
#if __has_builtin(__builtin_amdgcn_mfma_f32_16x16x16bf16_1k)
  return __builtin_amdgcn_mfma_f32_16x16x16bf16_1k(
      __builtin_bit_cast(short4v, a), __builtin_bit_cast(short4v, b), c, 0, 0, 0);
#else
  return __builtin_amdgcn_mfma_f32_16x16x16_bf16(a, b, c, 0, 0, 0);
#endif
#else
  return c;  // host pass: never executed
#endif
}

// ---------------------------------------------------------------- prep: all transposes + x cast
// z 0..3: Wq/Wk/Wv/Wo -> QKVT; z 4..7: W1 -> W1T; z 8..11: W2 -> W2T; z 12: cast x
__global__ __launch_bounds__(256)
void prep_kernel(const float* __restrict__ x,
                 const float* __restrict__ Wq, const float* __restrict__ Wk,
                 const float* __restrict__ Wv, const float* __restrict__ Wo,
                 const float* __restrict__ W1, const float* __restrict__ W2,
                 bf16* __restrict__ Xb, bf16* __restrict__ QKVT,
                 bf16* __restrict__ W1T, bf16* __restrict__ W2T)
{
  const int z = blockIdx.z;
  const int t = threadIdx.x;
  if (z == 12) {
    const size_t base = ((size_t)(blockIdx.y * 32 + blockIdx.x)) * 4096;
#pragma unroll
    for (int j = 0; j < 4; ++j) {
      const size_t i = base + j * 1024 + t * 4;
      f32x4 v = *(const f32x4*)(x + i);
      bf16x4 o;
#pragma unroll
      for (int k = 0; k < 4; ++k) o[k] = (bf16)v[k];
      *(bf16x4*)(Xb + i) = o;
    }
    return;
  }
  const float* ps; bf16* pd; int sld, dld;
  if (z < 4) {
    ps = (z == 0) ? Wq : (z == 1) ? Wk : (z == 2) ? Wv : Wo;
    pd = QKVT + (size_t)z * HDIM * HDIM; sld = 1024; dld = 1024;
  } else if (z < 8) {
    const int c = z - 4;
    ps = W1 + c * 1024; sld = 4096;
    pd = W1T + (size_t)c * 1024 * 1024; dld = 1024;
  } else {
    const int c = z - 8;
    ps = W2 + (size_t)c * 1024 * 1024; sld = 1024;
    pd = W2T + c * 1024; dld = 4096;
  }
  __shared__ float tile[32][33];
  const int tx = t & 31, ty = t >> 5;
  const int c0 = blockIdx.x * 32, r0 = blockIdx.y * 32;
#pragma unroll
  for (int i = 0; i < 32; i += 8)
    tile[ty + i][tx] = ps[(size_t)(r0 + ty + i) * sld + c0 + tx];
  __syncthreads();
#pragma unroll
  for (int i = 0; i < 32; i += 8)
    pd[(size_t)(c0 + ty + i) * dld + r0 + tx] = (bf16)tile[tx][ty + i];
}

// ---------------------------------------------------------------- GEMM  C = A @ Bt^T (+ bias)
// Operand-swapped MFMA: lane holds 4 consecutive output columns -> vector stores.
// EPI: 1 = bf16 partial (no bias, out + z*M*N), 2 = bias+gelu(A&S erf)->bf16,
//      3 = QKV fused epilogue (V -> Vt[d][s])
template<int EPI>
__global__ __launch_bounds__(256)
void gemm_bt(const bf16* __restrict__ A, const bf16* __restrict__ Bt,
             const float* __restrict__ b0, const float* __restrict__ b1p,
             const float* __restrict__ b2p, void* __restrict__ Cout,
             int M, int N, int ldk, int kchunk)
{
  __shared__ __align__(16) bf16 As[128 * 64];
  __shared__ __align__(16) bf16 Bs[128 * 64];
  const int t = threadIdx.x;
  const int wave = t >> 6, lane = t & 63;
  const int lm = lane & 15, qd = lane >> 4;
  const int wm = (wave >> 1) * 64, wn = (wave & 1) * 64;
  const int bm = blockIdx.y * 128, bn = blockIdx.x * 128;
  const int kbeg = blockIdx.z * kchunk;

  f32x4 acc[4][4] = {};
  const int srow = t >> 3;
  const int schk = t & 7;

  for (int k0 = kbeg; k0 < kbeg + kchunk; k0 += 64) {
#pragma unroll
    for (int r = 0; r < 4; ++r) {
      const int row = r * 32 + srow;
      const int chunk = schk ^ (row & 7);
      async_load16(A + (size_t)(bm + row) * ldk + (k0 + chunk * 8),
                   (bf16*)((char*)As + r * 4096 + t * 16));
    }
#pragma unroll
    for (int r = 0; r < 4; ++r) {
      const int row = r * 32 + srow;
      const int chunk = schk ^ (row & 7);
      async_load16(Bt + (size_t)(bn + row) * ldk + (k0 + chunk * 8),
                   (bf16*)((char*)Bs + r * 4096 + t * 16));
    }
    __syncthreads();
#pragma unroll
    for (int ks = 0; ks < 2; ++ks) {
      bf16x8 av[4], bv[4];
#pragma unroll
      for (int mt = 0; mt < 4; ++mt) {
        const int row = wm + mt * 16 + lm;
        const int chunk = (ks * 4 + qd) ^ (row & 7);
        av[mt] = *(const bf16x8*)(As + row * 64 + chunk * 8);
      }
#pragma unroll
      for (int nt = 0; nt < 4; ++nt) {
        const int row = wn + nt * 16 + lm;
        const int chunk = (ks * 4 + qd) ^ (row & 7);
        bv[nt] = *(const bf16x8*)(Bs + row * 64 + chunk * 8);
      }
#pragma unroll
      for (int mt = 0; mt < 4; ++mt)
#pragma unroll
        for (int nt = 0; nt < 4; ++nt)
          acc[mt][nt] = __builtin_amdgcn_mfma_f32_16x16x32_bf16(bv[nt], av[mt], acc[mt][nt], 0, 0, 0);
    }
    __syncthreads();
  }

#pragma unroll
  for (int nt = 0; nt < 4; ++nt) {
    const int n0 = bn + wn + nt * 16 + qd * 4;
    f32x4 bsv = {0.f, 0.f, 0.f, 0.f};
    if (EPI == 2) bsv = *(const f32x4*)(b0 + n0);
    if (EPI == 3) {
      const int sect = n0 >> 10, c = n0 & 1023;
      const float* bp = (sect == 0) ? b0 : (sect == 1) ? b1p : b2p;
      bsv = *(const f32x4*)(bp + c);
    }
#pragma unroll
    for (int mt = 0; mt < 4; ++mt) {
      const int m = bm + wm + mt * 16 + lm;
      f32x4 v;
#pragma unroll
      for (int r = 0; r < 4; ++r) v[r] = acc[mt][nt][r] + bsv[r];
      if (EPI == 1) {
        bf16x4 o;
#pragma unroll
        for (int r = 0; r < 4; ++r) o[r] = (bf16)v[r];
        *(bf16x4*)((bf16*)Cout + (size_t)blockIdx.z * M * N + (size_t)m * N + n0) = o;
      } else if (EPI == 2) {
        bf16x4 o;
#pragma unroll
        for (int r = 0; r < 4; ++r) {
          const float z = v[r] * 0.70710678118f;
          const float az = fabsf(z);
          const float tt = __builtin_amdgcn_rcpf(fmaf(az, 0.3275911f, 1.0f));
          const float poly = tt * fmaf(tt, fmaf(tt, fmaf(tt, fmaf(tt, 1.061405429f,
                             -1.453152027f), 1.421413741f), -0.284496736f), 0.254829592f);
          const float e = __builtin_amdgcn_exp2f(az * az * -1.4426950408889634f);
          float erfv = 1.0f - poly * e;
          erfv = (z < 0.f) ? -erfv : erfv;
          o[r] = (bf16)(0.5f * v[r] * (1.0f + erfv));
        }
        *(bf16x4*)((bf16*)Cout + (size_t)m * N + n0) = o;
      } else {
        bf16* base = (bf16*)Cout;
        const int sect = n0 >> 10, c = n0 & 1023;
        if (sect < 2) {
          bf16x4 o;
#pragma unroll
          for (int r = 0; r < 4; ++r) o[r] = (bf16)v[r];
          *(bf16x4*)(base + (size_t)sect * M_TOK * HDIM + (size_t)m * HDIM + c) = o;
        } else {
          const int hh = c >> 6, dd = c & 63;
          const int bb = m >> 11, ss = m & 2047;
#pragma unroll
          for (int r = 0; r < 4; ++r)
            base[(size_t)2 * M_TOK * HDIM +
                 (size_t)((bb * NHEAD + hh) * HD + dd + r) * SEQ + ss] = (bf16)v[r];
        }
      }
    }
  }
}

// ---------------------------------------------------------------- flash attention (R10 + XCD swizzle)
// LDS-staged K/V (64-key tiles), register-P, 32 q/wave, NSPLIT=4, bf16 partials.
// 1-D grid of 2048 blocks, decoded so all 16 q-blocks of one (bh,split) group
// share one XCD residue (lin mod 8) -> K/V slice stays in that XCD's L2.
__global__ __launch_bounds__(256)
void attn_kernel(const bf16* __restrict__ Q, const bf16* __restrict__ Kg,
                 const bf16* __restrict__ Vt, const int* __restrict__ mask,
                 bf16* __restrict__ Po, float* __restrict__ Lp)
{
  __shared__ __align__(16) bf16 Ks[64 * 64];   // [key][d], chunk-swizzled
  __shared__ __align__(16) bf16 Vs[64 * 64];   // [d][key], chunk-swizzled
  __shared__ float madd[64];

  const int t = threadIdx.x;
  const int wave = t >> 6, lane = t & 63;
  const int lm = lane & 15, qd = lane >> 4;

  // XCD-aware decode: group g = (lin&7)*16 + (lin>>7); qblk = (lin>>3)&15.
  // All blocks of group g have lin = (g>>4) mod 8 -> same XCD (round-robin heuristic).
  const int lin = blockIdx.x;
  const int g = (lin & 7) * 16 + (lin >> 7);
  const int qblk = (lin >> 3) & 15;
  const int bh = g >> 2;
  const int split = g & 3;
  const int b = bh >> 4, h = bh & 15;
  const int q0 = qblk * 128 + wave * 32;
  const int kv_beg = split * (SEQ / NSPLIT);

  bf16x8 qf[2][2];
#pragma unroll
  for (int qt = 0; qt < 2; ++qt)
#pragma unroll
    for (int ks = 0; ks < 2; ++ks)
      qf[qt][ks] = *(const bf16x8*)(Q + (size_t)(b * SEQ + q0 + qt * 16 + lm) * HDIM +
                                    h * HD + ks * 32 + qd * 8);

  float l_lane[2] = {0.f, 0.f};
  f32x4 oacc[2][4] = {};   // [qt][nt2] O^T: d = nt2*16+qd*4+r, q = lm

  const int srow = t >> 3, schk = t & 7;
  const float C = 0.1803368801f;  // log2(e)/8

  for (int kv0 = kv_beg; kv0 < kv_beg + SEQ / NSPLIT; kv0 += 64) {
#pragma unroll
    for (int r = 0; r < 2; ++r) {
      const int row = r * 32 + srow;
      const int g2 = schk ^ (row & 7);
      async_load16(Kg + (size_t)(b * SEQ + kv0 + row) * HDIM + h * HD + g2 * 8,
                   (bf16*)((char*)Ks + r * 4096 + t * 16));
      async_load16(Vt + (size_t)(bh * HD + row) * SEQ + kv0 + g2 * 8,
                   (bf16*)((char*)Vs + r * 4096 + t * 16));
    }
    if (t < 64) madd[t] = (mask[b * SEQ + kv0 + t] == 1) ? 0.f : -1.0e30f;
    __syncthreads();

    bf16x8 kf[2][4];
#pragma unroll
    for (int ks = 0; ks < 2; ++ks)
#pragma unroll
      for (int nt = 0; nt < 4; ++nt) {
        const int row = nt * 16 + lm;
        const int c = (ks * 4 + qd) ^ (row & 7);
        kf[ks][nt] = *(const bf16x8*)(Ks + row * 64 + c * 8);
      }

    bf16x4 pf[2][4];
#pragma unroll
    for (int qt = 0; qt < 2; ++qt) {
      f32x4 sacc[4] = {};
#pragma unroll
      for (int ks = 0; ks < 2; ++ks)
#pragma unroll
        for (int nt = 0; nt < 4; ++nt)
          sacc[nt] = __builtin_amdgcn_mfma_f32_16x16x32_bf16(kf[ks][nt], qf[qt][ks], sacc[nt], 0, 0, 0);
#pragma unroll
      for (int nt = 0; nt < 4; ++nt) {
        f32x4 ma = *(const f32x4*)(madd + nt * 16 + qd * 4);
#pragma unroll
        for (int r = 0; r < 4; ++r) {
          const float pv = __builtin_amdgcn_exp2f(fmaf(sacc[nt][r], C, ma[r]));
          l_lane[qt] += pv;
          pf[qt][nt][r] = (bf16)pv;
        }
      }
    }

#pragma unroll
    for (int nt2 = 0; nt2 < 4; ++nt2) {
      const int row = nt2 * 16 + lm;
#pragma unroll
      for (int nt = 0; nt < 4; ++nt) {
        bf16x4 vf = *(const bf16x4*)(Vs + row * 64 +
                     (((nt * 2 + (qd >> 1)) ^ (row & 7)) * 8) + (qd & 1) * 4);
        oacc[0][nt2] = mfma16_bf16(vf, pf[0][nt], oacc[0][nt2]);
        oacc[1][nt2] = mfma16_bf16(vf, pf[1][nt], oacc[1][nt2]);
      }
    }
    __syncthreads();
  }

  bf16* po = Po + (size_t)(split * 32 + bh) * 64 * SEQ;
#pragma unroll
  for (int qt = 0; qt < 2; ++qt) {
    float l = l_lane[qt];
    l += __shfl_xor(l, 16, 64);
    l += __shfl_xor(l, 32, 64);
#pragma unroll
    for (int nt2 = 0; nt2 < 4; ++nt2)
#pragma unroll
      for (int r = 0; r < 4; ++r)
        po[(size_t)(nt2 * 16 + qd * 4 + r) * SEQ + q0 + qt * 16 + lm] =
            (bf16)oacc[qt][nt2][r];
    if (qd == 0)
      Lp[(size_t)(split * 32 + bh) * SEQ + q0 + qt * 16 + lm] = l;
  }
}

// ---------------------------------------------------------------- attn merge: O = (sum Po_s)/(sum l_s)
__global__ __launch_bounds__(256)
void attn_merge(const bf16* __restrict__ Po, const float* __restrict__ Lp,
                bf16* __restrict__ Aout)
{
  const int t = threadIdx.x;
  const int bh = blockIdx.y;
  const int b = bh >> 4, h = bh & 15;
  const int s0 = blockIdx.x * 64;
  const int tok = t >> 2;
  const int dc = (t & 3) * 16;

  float l = 0.f;
#pragma unroll
  for (int s = 0; s < NSPLIT; ++s)
    l += Lp[(size_t)(s * 32 + bh) * SEQ + s0 + tok];
  const float inv = 1.0f / l;

  const bf16* ps[NSPLIT];
#pragma unroll
  for (int s = 0; s < NSPLIT; ++s)
    ps[s] = Po + (size_t)(s * 32 + bh) * 64 * SEQ + s0 + tok;

  bf16x8 o0, o1;
#pragma unroll
  for (int j = 0; j < 16; ++j) {
    float acc = 0.f;
#pragma unroll
    for (int s = 0; s < NSPLIT; ++s)
      acc += (float)ps[s][(size_t)(dc + j) * SEQ];
    const bf16 ov = (bf16)(acc * inv);
    if (j < 8) o0[j] = ov; else o1[j - 8] = ov;
  }

  bf16* dst = Aout + (size_t)(b * SEQ + s0 + tok) * HDIM + h * HD + dc;
  *(bf16x8*)dst = o0;
  *(bf16x8*)(dst + 8) = o1;
}

// ------------------------------- layernorm over H=1024, summing NP bf16 partials + bias
template<int NP, int OUT_BF16>
__global__ __launch_bounds__(256)
void ln_sum(const bf16* __restrict__ p, const float* __restrict__ bias,
            const float* __restrict__ gamma, const float* __restrict__ beta,
            void* __restrict__ out)
{
  const int row = blockIdx.x;
  const int t = threadIdx.x;
  f32x4 v = {0.f, 0.f, 0.f, 0.f};
#pragma unroll
  for (int np = 0; np < NP; ++np) {
    bf16x4 u = *(const bf16x4*)(p + np * PSTRIDE + (size_t)row * HDIM + t * 4);
#pragma unroll
    for (int j = 0; j < 4; ++j) v[j] += (float)u[j];
  }
  f32x4 bv0 = *(const f32x4*)(bias + t * 4);
#pragma unroll
  for (int j = 0; j < 4; ++j) v[j] += bv0[j];

  float s = v[0] + v[1] + v[2] + v[3];
  float s2 = v[0] * v[0] + v[1] * v[1] + v[2] * v[2] + v[3] * v[3];
#pragma unroll
  for (int d = 1; d < 64; d <<= 1) { s += __shfl_xor(s, d, 64); s2 += __shfl_xor(s2, d, 64); }
  __shared__ float ss[4], ss2[4];
  const int wave = t >> 6, lane = t & 63;
  if (lane == 0) { ss[wave] = s; ss2[wave] = s2; }
  __syncthreads();
  s = ss[0] + ss[1] + ss[2] + ss[3];
  s2 = ss2[0] + ss2[1] + ss2[2] + ss2[3];
  const float mean = s * (1.0f / HDIM);
  const float var = s2 * (1.0f / HDIM) - mean * mean;
  const float rstd = rsqrtf(var + 1e-12f);
  f32x4 gv = *(const f32x4*)(gamma + t * 4);
  f32x4 bv = *(const f32x4*)(beta + t * 4);
  f32x4 y;
#pragma unroll
  for (int j = 0; j < 4; ++j) y[j] = gv[j] * (v[j] - mean) * rstd + bv[j];
  if (OUT_BF16) {
    bf16x4 o;
#pragma unroll
    for (int j = 0; j < 4; ++j) o[j] = (bf16)y[j];
    *(bf16x4*)((bf16*)out + (size_t)row * HDIM + t * 4) = o;
  } else {
    *(f32x4*)((float*)out + (size_t)row * HDIM + t * 4) = y;
  }
}

// ---------------------------------------------------------------- launch
extern "C" void kernel_launch(void* const* d_in, const int* in_sizes, int n_in,
                              void* d_out, int out_size, void* d_ws, size_t ws_size,
                              hipStream_t stream)
{
  const float* x    = (const float*)d_in[0];
  const int*   am   = (const int*)d_in[1];
  const float* Wq   = (const float*)d_in[2];
  const float* bq   = (const float*)d_in[3];
  const float* Wk   = (const float*)d_in[4];
  const float* bk   = (const float*)d_in[5];
  const float* Wv   = (const float*)d_in[6];
  const float* bv   = (const float*)d_in[7];
  const float* Wo   = (const float*)d_in[8];
  const float* bo   = (const float*)d_in[9];
  const float* ln1g = (const float*)d_in[10];
  const float* ln1b = (const float*)d_in[11];
  const float* W1   = (const float*)d_in[12];
  const float* b1   = (const float*)d_in[13];
  const float* W2   = (const float*)d_in[14];
  const float* b2   = (const float*)d_in[15];
  const float* ln2g = (const float*)d_in[16];
  const float* ln2b = (const float*)d_in[17];

  char* ws = (char*)d_ws;
  const size_t MB = 1ull << 20;
  bf16*  W1T  = (bf16*)(ws + 0 * MB);    // 8 MiB
  bf16*  W2T  = (bf16*)(ws + 8 * MB);    // 8 MiB
  bf16*  Xb   = (bf16*)(ws + 16 * MB);   // 8 MiB (dead after QKV)
  bf16*  QKVT = (bf16*)(ws + 24 * MB);   // 8 MiB (WoT = last quarter)
  bf16*  WoT  = QKVT + (size_t)3 * HDIM * HDIM;
  bf16*  Qb   = (bf16*)(ws + 33 * MB);   // Q(33-41), K(41-49), Vt(49-57)
  bf16*  Kb   = (bf16*)(ws + 41 * MB);
  bf16*  Vtb  = (bf16*)(ws + 49 * MB);
  bf16*  Po   = (bf16*)(ws + 57 * MB);   // 32 MiB attn O^T bf16 partials (57-89)
  float* Lp   = (float*)(ws + 89 * MB);  // 1 MiB l partials (4 splits)
  bf16*  Ab   = (bf16*)(ws + 16 * MB);   // merge out, reuse Xb
  bf16*  Pw   = (bf16*)(ws + 33 * MB);   // Wo bf16 partials 33-49 (Q/K dead)
  bf16*  L1   = (bf16*)(ws + 65 * MB);   // 8 MiB
  bf16*  F1   = (bf16*)(ws + 16 * MB);   // 32 MiB (16-48)
  bf16*  Pf   = (bf16*)(ws + 48 * MB);   // FFN2 bf16 partials 48-80

  prep_kernel<<<dim3(32, 32, 13), 256, 0, stream>>>(x, Wq, Wk, Wv, Wo, W1, W2,
                                                    Xb, QKVT, W1T, W2T);

  gemm_bt<3><<<dim3(3072 / 128, M_TOK / 128, 1), 256, 0, stream>>>(
      Xb, QKVT, bq, bk, bv, Qb, M_TOK, 3072, HDIM, HDIM);

  attn_kernel<<<dim3(2048, 1, 1), 256, 0, stream>>>(Qb, Kb, Vtb, am, Po, Lp);
  attn_merge<<<dim3(SEQ / 64, BATCH * NHEAD), 256, 0, stream>>>(Po, Lp, Ab);

  gemm_bt<1><<<dim3(HDIM / 128, M_TOK / 128, 2), 256, 0, stream>>>(
      Ab, WoT, nullptr, nullptr, nullptr, Pw, M_TOK, HDIM, HDIM, 512);
  ln_sum<2, 1><<<M_TOK, 256, 0, stream>>>(Pw, bo, ln1g, ln1b, L1);

  gemm_bt<2><<<dim3(FFDIM / 128, M_TOK / 128, 1), 256, 0, stream>>>(
      L1, W1T, b1, nullptr, nullptr, F1, M_TOK, FFDIM, HDIM, HDIM);

  gemm_bt<1><<<dim3(HDIM / 128, M_TOK / 128, 4), 256, 0, stream>>>(
      F1, W2T, nullptr, nullptr, nullptr, Pf, M_TOK, HDIM, FFDIM, 1024);
  ln_sum<4, 0><<<M_TOK, 256, 0, stream>>>(Pf, b2, ln2g, ln2b, (float*)d_out);
}

// Round 14
// 358.818 us; speedup vs baseline: 1.0681x; 1.0397x over previous
//
#include <hip/hip_runtime.h>
#include <hip/hip_bf16.h>
#include <math.h>

typedef __bf16 bf16;
typedef __attribute__((ext_vector_type(8))) __bf16 bf16x8;
typedef __attribute__((ext_vector_type(4))) __bf16 bf16x4;
typedef __attribute__((ext_vector_type(2))) __bf16 bf16x2;
typedef __attribute__((ext_vector_type(4))) float f32x4;
typedef __attribute__((ext_vector_type(4))) short short4v;

#define HDIM 1024
#define NHEAD 16
#define HD 64
#define FFDIM 4096
#define BATCH 2
#define SEQ 2048
#define M_TOK 4096  // BATCH*SEQ
#define NSPLIT 4
#define PSTRIDE ((size_t)M_TOK * HDIM)  // elements between split-K partials

static __device__ __forceinline__ void async_load16(const bf16* g, bf16* l) {
  __builtin_amdgcn_global_load_lds(
      (const __attribute__((address_space(1))) void*)g,
      (__attribute__((address_space(3))) void*)l, 16, 0, 0);
}

// 16x16x16 bf16 MFMA wrapper. Host pass has no amdgcn builtins -> gate on
// __HIP_DEVICE_COMPILE__ (R5 lesson).
static __device__ __forceinline__ f32x4 mfma16_bf16(bf16x4 a, bf16x4 b, f32x4 c) {
#if defined(__HIP_DEVICE_COMPILE__)
#if __has_builtin(__builtin_amdgcn_mfma_f32_16x16x16bf16_1k)
  return __builtin_amdgcn_mfma_f32_16x16x16bf16_1k(
      __builtin_bit_cast(short4v, a), __builtin_bit_cast(short4v, b), c, 0, 0, 0);
#else
  return __builtin_amdgcn_mfma_f32_16x16x16_bf16(a, b, c, 0, 0, 0);
#endif
#else
  return c;  // host pass: never executed
#endif
}

// ---------------------------------------------------------------- prep: all transposes + x cast
// z 0..3: Wq/Wk/Wv/Wo -> QKVT; z 4..7: W1 -> W1T; z 8..11: W2 -> W2T; z 12: cast x
__global__ __launch_bounds__(256)
void prep_kernel(const float* __restrict__ x,
                 const float* __restrict__ Wq, const float* __restrict__ Wk,
                 const float* __restrict__ Wv, const float* __restrict__ Wo,
                 const float* __restrict__ W1, const float* __restrict__ W2,
                 bf16* __restrict__ Xb, bf16* __restrict__ QKVT,
                 bf16* __restrict__ W1T, bf16* __restrict__ W2T)
{
  const int z = blockIdx.z;
  const int t = threadIdx.x;
  if (z == 12) {
    const size_t base = ((size_t)(blockIdx.y * 32 + blockIdx.x)) * 4096;
#pragma unroll
    for (int j = 0; j < 4; ++j) {
      const size_t i = base + j * 1024 + t * 4;
      f32x4 v = *(const f32x4*)(x + i);
      bf16x4 o;
#pragma unroll
      for (int k = 0; k < 4; ++k) o[k] = (bf16)v[k];
      *(bf16x4*)(Xb + i) = o;
    }
    return;
  }
  const float* ps; bf16* pd; int sld, dld;
  if (z < 4) {
    ps = (z == 0) ? Wq : (z == 1) ? Wk : (z == 2) ? Wv : Wo;
    pd = QKVT + (size_t)z * HDIM * HDIM; sld = 1024; dld = 1024;
  } else if (z < 8) {
    const int c = z - 4;
    ps = W1 + c * 1024; sld = 4096;
    pd = W1T + (size_t)c * 1024 * 1024; dld = 1024;
  } else {
    const int c = z - 8;
    ps = W2 + (size_t)c * 1024 * 1024; sld = 1024;
    pd = W2T + c * 1024; dld = 4096;
  }
  __shared__ float tile[32][33];
  const int tx = t & 31, ty = t >> 5;
  const int c0 = blockIdx.x * 32, r0 = blockIdx.y * 32;
#pragma unroll
  for (int i = 0; i < 32; i += 8)
    tile[ty + i][tx] = ps[(size_t)(r0 + ty + i) * sld + c0 + tx];
  __syncthreads();
  // paired bf16x2 stores: lane t&15 owns src-row pair rr0, t>>4 selects dst row cc
  const int rr0 = (t & 15) * 2;
  const int ccb = t >> 4;  // 0..15
#pragma unroll
  for (int i = 0; i < 2; ++i) {
    const int cc = ccb + 16 * i;
    bf16x2 v = {(bf16)tile[rr0][cc], (bf16)tile[rr0 + 1][cc]};
    *(bf16x2*)(pd + (size_t)(c0 + cc) * dld + r0 + rr0) = v;
  }
}

// ---------------------------------------------------------------- GEMM  C = A @ Bt^T (+ bias)
// Operand-swapped MFMA: lane holds 4 consecutive output columns -> vector stores.
// EPI: 1 = bf16 partial (no bias, out + z*M*N), 2 = bias+gelu(A&S erf)->bf16,
//      3 = QKV fused epilogue (V -> Vt[d][s])
template<int EPI>
__global__ __launch_bounds__(256)
void gemm_bt(const bf16* __restrict__ A, const bf16* __restrict__ Bt,
             const float* __restrict__ b0, const float* __restrict__ b1p,
             const float* __restrict__ b2p, void* __restrict__ Cout,
             int M, int N, int ldk, int kchunk)
{
  __shared__ __align__(16) bf16 As[128 * 64];
  __shared__ __align__(16) bf16 Bs[128 * 64];
  const int t = threadIdx.x;
  const int wave = t >> 6, lane = t & 63;
  const int lm = lane & 15, qd = lane >> 4;
  const int wm = (wave >> 1) * 64, wn = (wave & 1) * 64;
  const int bm = blockIdx.y * 128, bn = blockIdx.x * 128;
  const int kbeg = blockIdx.z * kchunk;

  f32x4 acc[4][4] = {};
  const int srow = t >> 3;
  const int schk = t & 7;

  for (int k0 = kbeg; k0 < kbeg + kchunk; k0 += 64) {
#pragma unroll
    for (int r = 0; r < 4; ++r) {
      const int row = r * 32 + srow;
      const int chunk = schk ^ (row & 7);
      async_load16(A + (size_t)(bm + row) * ldk + (k0 + chunk * 8),
                   (bf16*)((char*)As + r * 4096 + t * 16));
    }
#pragma unroll
    for (int r = 0; r < 4; ++r) {
      const int row = r * 32 + srow;
      const int chunk = schk ^ (row & 7);
      async_load16(Bt + (size_t)(bn + row) * ldk + (k0 + chunk * 8),
                   (bf16*)((char*)Bs + r * 4096 + t * 16));
    }
    __syncthreads();
#pragma unroll
    for (int ks = 0; ks < 2; ++ks) {
      bf16x8 av[4], bv[4];
#pragma unroll
      for (int mt = 0; mt < 4; ++mt) {
        const int row = wm + mt * 16 + lm;
        const int chunk = (ks * 4 + qd) ^ (row & 7);
        av[mt] = *(const bf16x8*)(As + row * 64 + chunk * 8);
      }
#pragma unroll
      for (int nt = 0; nt < 4; ++nt) {
        const int row = wn + nt * 16 + lm;
        const int chunk = (ks * 4 + qd) ^ (row & 7);
        bv[nt] = *(const bf16x8*)(Bs + row * 64 + chunk * 8);
      }
#pragma unroll
      for (int mt = 0; mt < 4; ++mt)
#pragma unroll
        for (int nt = 0; nt < 4; ++nt)
          acc[mt][nt] = __builtin_amdgcn_mfma_f32_16x16x32_bf16(bv[nt], av[mt], acc[mt][nt], 0, 0, 0);
    }
    __syncthreads();
  }

#pragma unroll
  for (int nt = 0; nt < 4; ++nt) {
    const int n0 = bn + wn + nt * 16 + qd * 4;
    f32x4 bsv = {0.f, 0.f, 0.f, 0.f};
    if (EPI == 2) bsv = *(const f32x4*)(b0 + n0);
    if (EPI == 3) {
      const int sect = n0 >> 10, c = n0 & 1023;
      const float* bp = (sect == 0) ? b0 : (sect == 1) ? b1p : b2p;
      bsv = *(const f32x4*)(bp + c);
    }
#pragma unroll
    for (int mt = 0; mt < 4; ++mt) {
      const int m = bm + wm + mt * 16 + lm;
      f32x4 v;
#pragma unroll
      for (int r = 0; r < 4; ++r) v[r] = acc[mt][nt][r] + bsv[r];
      if (EPI == 1) {
        bf16x4 o;
#pragma unroll
        for (int r = 0; r < 4; ++r) o[r] = (bf16)v[r];
        *(bf16x4*)((bf16*)Cout + (size_t)blockIdx.z * M * N + (size_t)m * N + n0) = o;
      } else if (EPI == 2) {
        bf16x4 o;
#pragma unroll
        for (int r = 0; r < 4; ++r) {
          const float z = v[r] * 0.70710678118f;
          const float az = fabsf(z);
          const float tt = __builtin_amdgcn_rcpf(fmaf(az, 0.3275911f, 1.0f));
          const float poly = tt * fmaf(tt, fmaf(tt, fmaf(tt, fmaf(tt, 1.061405429f,
                             -1.453152027f), 1.421413741f), -0.284496736f), 0.254829592f);
          const float e = __builtin_amdgcn_exp2f(az * az * -1.4426950408889634f);
          float erfv = 1.0f - poly * e;
          erfv = (z < 0.f) ? -erfv : erfv;
          o[r] = (bf16)(0.5f * v[r] * (1.0f + erfv));
        }
        *(bf16x4*)((bf16*)Cout + (size_t)m * N + n0) = o;
      } else {
        bf16* base = (bf16*)Cout;
        const int sect = n0 >> 10, c = n0 & 1023;
        if (sect < 2) {
          bf16x4 o;
#pragma unroll
          for (int r = 0; r < 4; ++r) o[r] = (bf16)v[r];
          *(bf16x4*)(base + (size_t)sect * M_TOK * HDIM + (size_t)m * HDIM + c) = o;
        } else {
          const int hh = c >> 6, dd = c & 63;
          const int bb = m >> 11, ss = m & 2047;
#pragma unroll
          for (int r = 0; r < 4; ++r)
            base[(size_t)2 * M_TOK * HDIM +
                 (size_t)((bb * NHEAD + hh) * HD + dd + r) * SEQ + ss] = (bf16)v[r];
        }
      }
    }
  }
}

// ---------------------------------------------------------------- flash attention
// R13 (LDS-staged K/V, register-P, 32 q/wave, XCD swizzle, bf16 partials)
// + l accumulated on the MFMA pipe via ones-matrix (removes 32 VALU adds/tile
//   and the end shuffles; denominator rounding now matches bf16 numerator).
__global__ __launch_bounds__(256)
void attn_kernel(const bf16* __restrict__ Q, const bf16* __restrict__ Kg,
                 const bf16* __restrict__ Vt, const int* __restrict__ mask,
                 bf16* __restrict__ Po, float* __restrict__ Lp)
{
  __shared__ __align__(16) bf16 Ks[64 * 64];   // [key][d], chunk-swizzled
  __shared__ __align__(16) bf16 Vs[64 * 64];   // [d][key], chunk-swizzled
  __shared__ float madd[64];

  const int t = threadIdx.x;
  const int wave = t >> 6, lane = t & 63;
  const int lm = lane & 15, qd = lane >> 4;

  // XCD-aware decode: group g = (lin&7)*16 + (lin>>7); qblk = (lin>>3)&15.
  const int lin = blockIdx.x;
  const int g = (lin & 7) * 16 + (lin >> 7);
  const int qblk = (lin >> 3) & 15;
  const int bh = g >> 2;
  const int split = g & 3;
  const int b = bh >> 4, h = bh & 15;
  const int q0 = qblk * 128 + wave * 32;
  const int kv_beg = split * (SEQ / NSPLIT);

  bf16x8 qf[2][2];
#pragma unroll
  for (int qt = 0; qt < 2; ++qt)
#pragma unroll
    for (int ks = 0; ks < 2; ++ks)
      qf[qt][ks] = *(const bf16x8*)(Q + (size_t)(b * SEQ + q0 + qt * 16 + lm) * HDIM +
                                    h * HD + ks * 32 + qd * 8);

  const bf16 onev = (bf16)1.0f;
  const bf16x4 ones = {onev, onev, onev, onev};
  f32x4 lacc[2] = {};      // l via MFMA: all entries = colsum for q=lm
  f32x4 oacc[2][4] = {};   // [qt][nt2] O^T: d = nt2*16+qd*4+r, q = lm

  const int srow = t >> 3, schk = t & 7;
  const float C = 0.1803368801f;  // log2(e)/8

  for (int kv0 = kv_beg; kv0 < kv_beg + SEQ / NSPLIT; kv0 += 64) {
#pragma unroll
    for (int r = 0; r < 2; ++r) {
      const int row = r * 32 + srow;
      const int g2 = schk ^ (row & 7);
      async_load16(Kg + (size_t)(b * SEQ + kv0 + row) * HDIM + h * HD + g2 * 8,
                   (bf16*)((char*)Ks + r * 4096 + t * 16));
      async_load16(Vt + (size_t)(bh * HD + row) * SEQ + kv0 + g2 * 8,
                   (bf16*)((char*)Vs + r * 4096 + t * 16));
    }
    if (t < 64) madd[t] = (mask[b * SEQ + kv0 + t] == 1) ? 0.f : -1.0e30f;
    __syncthreads();

    bf16x8 kf[2][4];
#pragma unroll
    for (int ks = 0; ks < 2; ++ks)
#pragma unroll
      for (int nt = 0; nt < 4; ++nt) {
        const int row = nt * 16 + lm;
        const int c = (ks * 4 + qd) ^ (row & 7);
        kf[ks][nt] = *(const bf16x8*)(Ks + row * 64 + c * 8);
      }

    bf16x4 pf[2][4];
#pragma unroll
    for (int qt = 0; qt < 2; ++qt) {
      f32x4 sacc[4] = {};
#pragma unroll
      for (int ks = 0; ks < 2; ++ks)
#pragma unroll
        for (int nt = 0; nt < 4; ++nt)
          sacc[nt] = __builtin_amdgcn_mfma_f32_16x16x32_bf16(kf[ks][nt], qf[qt][ks], sacc[nt], 0, 0, 0);
#pragma unroll
      for (int nt = 0; nt < 4; ++nt) {
        f32x4 ma = *(const f32x4*)(madd + nt * 16 + qd * 4);
#pragma unroll
        for (int r = 0; r < 4; ++r)
          pf[qt][nt][r] = (bf16)__builtin_amdgcn_exp2f(fmaf(sacc[nt][r], C, ma[r]));
        lacc[qt] = mfma16_bf16(ones, pf[qt][nt], lacc[qt]);
      }
    }

#pragma unroll
    for (int nt2 = 0; nt2 < 4; ++nt2) {
      const int row = nt2 * 16 + lm;
#pragma unroll
      for (int nt = 0; nt < 4; ++nt) {
        bf16x4 vf = *(const bf16x4*)(Vs + row * 64 +
                     (((nt * 2 + (qd >> 1)) ^ (row & 7)) * 8) + (qd & 1) * 4);
        oacc[0][nt2] = mfma16_bf16(vf, pf[0][nt], oacc[0][nt2]);
        oacc[1][nt2] = mfma16_bf16(vf, pf[1][nt], oacc[1][nt2]);
      }
    }
    __syncthreads();
  }

  bf16* po = Po + (size_t)(split * 32 + bh) * 64 * SEQ;
#pragma unroll
  for (int qt = 0; qt < 2; ++qt) {
#pragma unroll
    for (int nt2 = 0; nt2 < 4; ++nt2)
#pragma unroll
      for (int r = 0; r < 4; ++r)
        po[(size_t)(nt2 * 16 + qd * 4 + r) * SEQ + q0 + qt * 16 + lm] =
            (bf16)oacc[qt][nt2][r];
    if (qd == 0)
      Lp[(size_t)(split * 32 + bh) * SEQ + q0 + qt * 16 + lm] = lacc[qt][0];
  }
}

// ------------------------------- attn merge via LDS tile: coalesced reads along s
__global__ __launch_bounds__(256)
void attn_merge(const bf16* __restrict__ Po, const float* __restrict__ Lp,
                bf16* __restrict__ Aout)
{
  __shared__ bf16 tile[64][80];  // [s][d], 80-elem rows -> 160B, 16B-aligned
  __shared__ float linv[64];
  const int t = threadIdx.x;
  const int bh = blockIdx.y;
  const int b = bh >> 4, h = bh & 15;
  const int s0 = blockIdx.x * 64;

  if (t < 64) {
    float l = 0.f;
#pragma unroll
    for (int s = 0; s < NSPLIT; ++s)
      l += Lp[(size_t)(s * 32 + bh) * SEQ + s0 + t];
    linv[t] = 1.0f / l;
  }
  __syncthreads();

#pragma unroll
  for (int it = 0; it < 2; ++it) {
    const int d = (t >> 3) + 32 * it;
    const int sc = (t & 7) * 8;
    float acc[8] = {};
#pragma unroll
    for (int s = 0; s < NSPLIT; ++s) {
      bf16x8 v = *(const bf16x8*)(Po + ((size_t)(s * 32 + bh) * 64 + d) * SEQ + s0 + sc);
#pragma unroll
      for (int j = 0; j < 8; ++j) acc[j] += (float)v[j];
    }
#pragma unroll
    for (int j = 0; j < 8; ++j)
      tile[sc + j][d] = (bf16)(acc[j] * linv[sc + j]);
  }
  __syncthreads();

  const int tok = t >> 2, dc = (t & 3) * 16;
  bf16x8 o0 = *(const bf16x8*)&tile[tok][dc];
  bf16x8 o1 = *(const bf16x8*)&tile[tok][dc + 8];
  bf16* dst = Aout + (size_t)(b * SEQ + s0 + tok) * HDIM + h * HD + dc;
  *(bf16x8*)dst = o0;
  *(bf16x8*)(dst + 8) = o1;
}

// ------------------------------- layernorm over H=1024, summing NP bf16 partials + bias
template<int NP, int OUT_BF16>
__global__ __launch_bounds__(256)
void ln_sum(const bf16* __restrict__ p, const float* __restrict__ bias,
            const float* __restrict__ gamma, const float* __restrict__ beta,
            void* __restrict__ out)
{
  const int row = blockIdx.x;
  const int t = threadIdx.x;
  f32x4 v = {0.f, 0.f, 0.f, 0.f};
#pragma unroll
  for (int np = 0; np < NP; ++np) {
    bf16x4 u = *(const bf16x4*)(p + np * PSTRIDE + (size_t)row * HDIM + t * 4);
#pragma unroll
    for (int j = 0; j < 4; ++j) v[j] += (float)u[j];
  }
  f32x4 bv0 = *(const f32x4*)(bias + t * 4);
#pragma unroll
  for (int j = 0; j < 4; ++j) v[j] += bv0[j];

  float s = v[0] + v[1] + v[2] + v[3];
  float s2 = v[0] * v[0] + v[1] * v[1] + v[2] * v[2] + v[3] * v[3];
#pragma unroll
  for (int d = 1; d < 64; d <<= 1) { s += __shfl_xor(s, d, 64); s2 += __shfl_xor(s2, d, 64); }
  __shared__ float ss[4], ss2[4];
  const int wave = t >> 6, lane = t & 63;
  if (lane == 0) { ss[wave] = s; ss2[wave] = s2; }
  __syncthreads();
  s = ss[0] + ss[1] + ss[2] + ss[3];
  s2 = ss2[0] + ss2[1] + ss2[2] + ss2[3];
  const float mean = s * (1.0f / HDIM);
  const float var = s2 * (1.0f / HDIM) - mean * mean;
  const float rstd = rsqrtf(var + 1e-12f);
  f32x4 gv = *(const f32x4*)(gamma + t * 4);
  f32x4 bv = *(const f32x4*)(beta + t * 4);
  f32x4 y;
#pragma unroll
  for (int j = 0; j < 4; ++j) y[j] = gv[j] * (v[j] - mean) * rstd + bv[j];
  if (OUT_BF16) {
    bf16x4 o;
#pragma unroll
    for (int j = 0; j < 4; ++j) o[j] = (bf16)y[j];
    *(bf16x4*)((bf16*)out + (size_t)row * HDIM + t * 4) = o;
  } else {
    *(f32x4*)((float*)out + (size_t)row * HDIM + t * 4) = y;
  }
}

// ---------------------------------------------------------------- launch
extern "C" void kernel_launch(void* const* d_in, const int* in_sizes, int n_in,
                              void* d_out, int out_size, void* d_ws, size_t ws_size,
                              hipStream_t stream)
{
  const float* x    = (const float*)d_in[0];
  const int*   am   = (const int*)d_in[1];
  const float* Wq   = (const float*)d_in[2];
  const float* bq   = (const float*)d_in[3];
  const float* Wk   = (const float*)d_in[4];
  const float* bk   = (const float*)d_in[5];
  const float* Wv   = (const float*)d_in[6];
  const float* bv   = (const float*)d_in[7];
  const float* Wo   = (const float*)d_in[8];
  const float* bo   = (const float*)d_in[9];
  const float* ln1g = (const float*)d_in[10];
  const float* ln1b = (const float*)d_in[11];
  const float* W1   = (const float*)d_in[12];
  const float* b1   = (const float*)d_in[13];
  const float* W2   = (const float*)d_in[14];
  const float* b2   = (const float*)d_in[15];
  const float* ln2g = (const float*)d_in[16];
  const float* ln2b = (const float*)d_in[17];

  char* ws = (char*)d_ws;
  const size_t MB = 1ull << 20;
  bf16*  W1T  = (bf16*)(ws + 0 * MB);    // 8 MiB
  bf16*  W2T  = (bf16*)(ws + 8 * MB);    // 8 MiB
  bf16*  Xb   = (bf16*)(ws + 16 * MB);   // 8 MiB (dead after QKV)
  bf16*  QKVT = (bf16*)(ws + 24 * MB);   // 8 MiB (WoT = last quarter)
  bf16*  WoT  = QKVT + (size_t)3 * HDIM * HDIM;
  bf16*  Qb   = (bf16*)(ws + 33 * MB);   // Q(33-41), K(41-49), Vt(49-57)
  bf16*  Kb   = (bf16*)(ws + 41 * MB);
  bf16*  Vtb  = (bf16*)(ws + 49 * MB);
  bf16*  Po   = (bf16*)(ws + 57 * MB);   // 32 MiB attn O^T bf16 partials (57-89)
  float* Lp   = (float*)(ws + 89 * MB);  // 1 MiB l partials (4 splits)
  bf16*  Ab   = (bf16*)(ws + 16 * MB);   // merge out, reuse Xb
  bf16*  Pw   = (bf16*)(ws + 33 * MB);   // Wo bf16 partials 33-49 (Q/K dead)
  bf16*  L1   = (bf16*)(ws + 65 * MB);   // 8 MiB
  bf16*  F1   = (bf16*)(ws + 16 * MB);   // 32 MiB (16-48)
  bf16*  Pf   = (bf16*)(ws + 48 * MB);   // FFN2 bf16 partials 48-80

  prep_kernel<<<dim3(32, 32, 13), 256, 0, stream>>>(x, Wq, Wk, Wv, Wo, W1, W2,
                                                    Xb, QKVT, W1T, W2T);

  gemm_bt<3><<<dim3(3072 / 128, M_TOK / 128, 1), 256, 0, stream>>>(
      Xb, QKVT, bq, bk, bv, Qb, M_TOK, 3072, HDIM, HDIM);

  attn_kernel<<<dim3(2048, 1, 1), 256, 0, stream>>>(Qb, Kb, Vtb, am, Po, Lp);
  attn_merge<<<dim3(SEQ / 64, BATCH * NHEAD), 256, 0, stream>>>(Po, Lp, Ab);

  gemm_bt<1><<<dim3(HDIM / 128, M_TOK / 128, 2), 256, 0, stream>>>(
      Ab, WoT, nullptr, nullptr, nullptr, Pw, M_TOK, HDIM, HDIM, 512);
  ln_sum<2, 1><<<M_TOK, 256, 0, stream>>>(Pw, bo, ln1g, ln1b, L1);

  gemm_bt<2><<<dim3(FFDIM / 128, M_TOK / 128, 1), 256, 0, stream>>>(
      L1, W1T, b1, nullptr, nullptr, F1, M_TOK, FFDIM, HDIM, HDIM);

  gemm_bt<1><<<dim3(HDIM / 128, M_TOK / 128, 4), 256, 0, stream>>>(
      F1, W2T, nullptr, nullptr, nullptr, Pf, M_TOK, HDIM, FFDIM, 1024);
  ln_sum<4, 0><<<M_TOK, 256, 0, stream>>>(Pf, b2, ln2g, ln2b, (float*)d_out);
}